// Round 11
// baseline (1516.569 us; speedup 1.0000x reference)
//
#include <hip/hip_runtime.h>
#include <cmath>

#define NFEAT 350
#define DMODEL 512
#define NLAYER 4
#define DSZ 64
#define REG_E 32
#define BATCH 32
#define SEQ 2048
#define MTOK (BATCH * SEQ)      // 65536
#define CLAMP_V 20.0f

#define CHUNK 64
#define NCHUNK (SEQ / CHUNK)    // 32

typedef short bf16x8 __attribute__((ext_vector_type(8)));
typedef float f32x4 __attribute__((ext_vector_type(4)));

__device__ __forceinline__ unsigned short f2b(float v) {
    union { float f; unsigned int u; } x; x.f = v;
    unsigned int r = x.u + 0x7fffu + ((x.u >> 16) & 1u);
    return (unsigned short)(r >> 16);
}
__device__ __forceinline__ float b2f(unsigned short u) {
    union { unsigned int i; float f; } x; x.i = ((unsigned int)u) << 16;
    return x.f;
}
__device__ __forceinline__ unsigned int pack2(float a, float b) {
    return ((unsigned int)f2b(b) << 16) | f2b(a);
}

// ---------------- weight preconvert: dst[n][k] = bf16(src[k][n]), zero-padded ----------------
__global__ __launch_bounds__(256) void tconv_k(const float* __restrict__ src,
                                               unsigned short* __restrict__ dst,
                                               int K, int N, int Kpad) {
    int k = blockIdx.x * 256 + threadIdx.x;
    int n = blockIdx.y;
    if (k >= Kpad) return;
    float v = (k < K && n < N) ? src[(size_t)k * N + n] : 0.f;
    dst[(size_t)n * Kpad + k] = f2b(v);
}

// gates weights: z = l*4+g; src [512][64] -> dst[z][64 n][512 k]
__global__ __launch_bounds__(256) void tconv_g_k(const float* __restrict__ wi,
                                                 const float* __restrict__ wf,
                                                 const float* __restrict__ wz,
                                                 const float* __restrict__ wo,
                                                 unsigned short* __restrict__ dst) {
    int k = blockIdx.x * 256 + threadIdx.x;
    int n = blockIdx.y;
    int z = blockIdx.z;
    int l = z >> 2, g = z & 3;
    const float* src = (g == 0 ? wi : g == 1 ? wf : g == 2 ? wz : wo) + (size_t)l * DMODEL * DSZ;
    dst[(size_t)z * 32768 + (size_t)n * 512 + k] = f2b(src[(size_t)k * DSZ + n]);
}

__global__ __launch_bounds__(1024) void gbias_k(const float* bi, const float* bf_,
                                                const float* bz, const float* bo,
                                                float* __restrict__ gbias) {
    int t = threadIdx.x;                 // 1024 = L*256
    int l = t >> 8, r = t & 255, g = r >> 6, e = r & 63;
    const float* s = (g == 0 ? bi : g == 1 ? bf_ : g == 2 ? bz : bo);
    gbias[t] = s[l * 64 + e];
}

// ---------------- xc = bf16(concat(x, emb[rid], 0)) [MTOK][384] ----------------
__global__ __launch_bounds__(256) void build_xc_k(const float* __restrict__ x,
                                                  const int* __restrict__ rid,
                                                  const float* __restrict__ emb,
                                                  unsigned short* __restrict__ xc) {
    int i = blockIdx.x * 256 + threadIdx.x;      // MTOK*192
    int m = i / 192, p = i - m * 192;
    int k = p * 2;
    float a = 0.f, b = 0.f;
    if (k < 350) {
        const float2 v = *(const float2*)(x + (size_t)m * NFEAT + k);
        a = v.x; b = v.y;
    } else if (k < 382) {
        int r = rid[m];
        const float2 v = *(const float2*)(emb + r * REG_E + (k - 350));
        a = v.x; b = v.y;
    }
    ((unsigned int*)xc)[(size_t)m * 192 + p] = pack2(a, b);
}

// ---------------- MFMA GEMM: C = epi(A @ Bt^T' + bias) ----------------
// ALD 0: A bf16 [M][lda], direct 16B staging.
// ALD 1: A f32 [M][lda]; stage LN(A)= (a-mu[row])*rstd[row]*lng[k]+lnb[k] -> bf16.
// Bt [Npad][ldb] bf16 (row n = column n of B, k-contiguous).
// Tile 128x128x32, 256 threads = 4 waves (2x2 of 64x64).
// EPI 0: elu -> bf16 | 1: none -> bf16 | 2: gate act by n>>6 -> f32 | 3: none -> f32
//   EPI 3 extra: if statS != nullptr, accumulate per-token row sums S=Σv, Q=Σv² via
//   16-lane shfl reduce + atomicAdd (fuses ln_stats; finalized by ln_fin_k).
template <int ALD, int EPI>
__global__ __launch_bounds__(256) void mgemm_k(const unsigned short* __restrict__ Ab,
                                               const float* __restrict__ Af,
                                               const unsigned short* __restrict__ Bt,
                                               const float* __restrict__ bias,
                                               float* __restrict__ Cf,
                                               unsigned short* __restrict__ Cb,
                                               const float* __restrict__ muA,
                                               const float* __restrict__ rstdA,
                                               const float* __restrict__ lng,
                                               const float* __restrict__ lnb,
                                               float* __restrict__ statS,
                                               float* __restrict__ statQ,
                                               int lda, int ldb, int K, int N, int ldc) {
    __shared__ unsigned short As[128][40];   // 80B row stride: 16B-aligned, 2-way banks (free)
    __shared__ unsigned short Bs[128][40];
    const int tid = threadIdx.x;
    const int lane = tid & 63;
    const int wave = tid >> 6;
    const int l15 = lane & 15;
    const int quad = lane >> 4;
    const int wm = (wave >> 1) * 64;
    const int wn = (wave & 1) * 64;
    const size_t m0 = (size_t)blockIdx.y * 128;
    const int n0 = blockIdx.x * 128;

    const int sr = tid >> 2;                 // 0..63
    const int ku = tid & 3;                  // k-unit (8 elements)

    const unsigned short* Br0 = Bt + ((size_t)(n0 + sr)) * ldb + ku * 8;
    const unsigned short* Br1 = Br0 + (size_t)64 * ldb;

    const unsigned short* Ar0 = nullptr;
    const unsigned short* Ar1 = nullptr;
    const float* Fr0 = nullptr;
    const float* Fr1 = nullptr;
    float mu0 = 0.f, rs0 = 0.f, mu1 = 0.f, rs1 = 0.f;
    if (ALD == 0) {
        Ar0 = Ab + (m0 + sr) * (size_t)lda + ku * 8;
        Ar1 = Ar0 + (size_t)64 * lda;
    } else {
        Fr0 = Af + (m0 + sr) * (size_t)lda + ku * 8;
        Fr1 = Fr0 + (size_t)64 * lda;
        mu0 = muA[m0 + sr];   rs0 = rstdA[m0 + sr];
        mu1 = muA[m0 + sr + 64]; rs1 = rstdA[m0 + sr + 64];
    }

    f32x4 acc[4][4] = {};

    for (int k0 = 0; k0 < K; k0 += 32) {
        if (ALD == 0) {
            *(uint4*)&As[sr][ku * 8]      = *(const uint4*)(Ar0 + k0);
            *(uint4*)&As[sr + 64][ku * 8] = *(const uint4*)(Ar1 + k0);
        } else {
            float4 g0 = *(const float4*)(lng + k0 + ku * 8);
            float4 g1 = *(const float4*)(lng + k0 + ku * 8 + 4);
            float4 c0 = *(const float4*)(lnb + k0 + ku * 8);
            float4 c1 = *(const float4*)(lnb + k0 + ku * 8 + 4);
            {
                float4 v0 = *(const float4*)(Fr0 + k0);
                float4 v1 = *(const float4*)(Fr0 + k0 + 4);
                uint4 w;
                w.x = pack2((v0.x - mu0) * rs0 * g0.x + c0.x, (v0.y - mu0) * rs0 * g0.y + c0.y);
                w.y = pack2((v0.z - mu0) * rs0 * g0.z + c0.z, (v0.w - mu0) * rs0 * g0.w + c0.w);
                w.z = pack2((v1.x - mu0) * rs0 * g1.x + c1.x, (v1.y - mu0) * rs0 * g1.y + c1.y);
                w.w = pack2((v1.z - mu0) * rs0 * g1.z + c1.z, (v1.w - mu0) * rs0 * g1.w + c1.w);
                *(uint4*)&As[sr][ku * 8] = w;
            }
            {
                float4 v0 = *(const float4*)(Fr1 + k0);
                float4 v1 = *(const float4*)(Fr1 + k0 + 4);
                uint4 w;
                w.x = pack2((v0.x - mu1) * rs1 * g0.x + c0.x, (v0.y - mu1) * rs1 * g0.y + c0.y);
                w.y = pack2((v0.z - mu1) * rs1 * g0.z + c0.z, (v0.w - mu1) * rs1 * g0.w + c0.w);
                w.z = pack2((v1.x - mu1) * rs1 * g1.x + c1.x, (v1.y - mu1) * rs1 * g1.y + c1.y);
                w.w = pack2((v1.z - mu1) * rs1 * g1.z + c1.z, (v1.w - mu1) * rs1 * g1.w + c1.w);
                *(uint4*)&As[sr + 64][ku * 8] = w;
            }
        }
        *(uint4*)&Bs[sr][ku * 8]      = *(const uint4*)(Br0 + k0);
        *(uint4*)&Bs[sr + 64][ku * 8] = *(const uint4*)(Br1 + k0);
        __syncthreads();
        bf16x8 af[4], bf[4];
#pragma unroll
        for (int mt = 0; mt < 4; mt++)
            af[mt] = *(const bf16x8*)&As[wm + mt * 16 + l15][quad * 8];
#pragma unroll
        for (int nt = 0; nt < 4; nt++)
            bf[nt] = *(const bf16x8*)&Bs[wn + nt * 16 + l15][quad * 8];
#pragma unroll
        for (int mt = 0; mt < 4; mt++)
#pragma unroll
            for (int nt = 0; nt < 4; nt++)
                acc[mt][nt] = __builtin_amdgcn_mfma_f32_16x16x32_bf16(af[mt], bf[nt], acc[mt][nt], 0, 0, 0);
        __syncthreads();
    }

    float sA[4][4] = {}, qA[4][4] = {};

#pragma unroll
    for (int mt = 0; mt < 4; mt++) {
        int gmb = wm + mt * 16 + quad * 4;
#pragma unroll
        for (int nt = 0; nt < 4; nt++) {
            int gn = n0 + wn + nt * 16 + l15;
            if (gn < N) {
                float bv = bias[gn];
#pragma unroll
                for (int r = 0; r < 4; r++) {
                    size_t gm = m0 + gmb + r;
                    float v = acc[mt][nt][r] + bv;
                    if (EPI == 0) {
                        v = v > 0.f ? v : expm1f(v);
                        Cb[gm * (size_t)ldc + gn] = f2b(v);
                    } else if (EPI == 1) {
                        Cb[gm * (size_t)ldc + gn] = f2b(v);
                    } else if (EPI == 2) {
                        int g = gn >> 6;
                        if (g < 2) v = fminf(fmaxf(v, -CLAMP_V), CLAMP_V);
                        else if (g == 2) v = tanhf(v);
                        else v = 1.f / (1.f + expf(-v));
                        Cf[gm * (size_t)ldc + gn] = v;
                    } else {
                        Cf[gm * (size_t)ldc + gn] = v;
                        sA[mt][r] += v;
                        qA[mt][r] += v * v;
                    }
                }
            }
        }
    }

    if (EPI == 3 && statS != nullptr) {
#pragma unroll
        for (int mt = 0; mt < 4; mt++)
#pragma unroll
            for (int r = 0; r < 4; r++) {
                float s = sA[mt][r], q = qA[mt][r];
#pragma unroll
                for (int o = 1; o < 16; o <<= 1) {
                    s += __shfl_xor(s, o, 64);
                    q += __shfl_xor(q, o, 64);
                }
                if (l15 == 0) {
                    size_t gm = m0 + wm + mt * 16 + quad * 4 + r;
                    atomicAdd(&statS[gm], s);
                    atomicAdd(&statQ[gm], q);
                }
            }
    }
}

// finalize fused LN stats: (S, Q) -> (mu, rstd)
__global__ __launch_bounds__(256) void ln_fin_k(const float* __restrict__ statS,
                                                const float* __restrict__ statQ,
                                                float* __restrict__ mu,
                                                float* __restrict__ rstd) {
    int tok = blockIdx.x * 256 + threadIdx.x;
    float s = statS[tok], q = statQ[tok];
    float m = s * (1.f / DMODEL);
    float v = q * (1.f / DMODEL) - m * m;
    mu[tok] = m;
    rstd[tok] = rsqrtf(v + 1e-5f);
}

// ---------------- softmax over bf16 logits; writes xw=w*x in-place into xc; emits w last row ----------------
__global__ __launch_bounds__(256) void softmax_xw_k(const unsigned short* __restrict__ logits,
                                                    unsigned short* __restrict__ xc,
                                                    float* __restrict__ out_wlast) {
    int tok = blockIdx.x * 4 + (threadIdx.x >> 6);
    int lane = threadIdx.x & 63;
    const unsigned short* lr = logits + (size_t)tok * NFEAT;
    unsigned short* xr = xc + (size_t)tok * 384;
    float v[6];
    float mx = -1e30f;
#pragma unroll
    for (int i = 0; i < 6; i++) {
        int idx = lane + 64 * i;
        v[i] = (idx < NFEAT) ? b2f(lr[idx]) : -1e30f;
        mx = fmaxf(mx, v[i]);
    }
#pragma unroll
    for (int o = 32; o > 0; o >>= 1) mx = fmaxf(mx, __shfl_xor(mx, o, 64));
    float s = 0.f;
#pragma unroll
    for (int i = 0; i < 6; i++) { v[i] = expf(v[i] - mx); s += v[i]; }
#pragma unroll
    for (int o = 32; o > 0; o >>= 1) s += __shfl_xor(s, o, 64);
    float inv = 1.f / s;
    bool last = ((tok & (SEQ - 1)) == SEQ - 1);
    int b = tok >> 11;
#pragma unroll
    for (int i = 0; i < 6; i++) {
        int idx = lane + 64 * i;
        if (idx < NFEAT) {
            float w = v[i] * inv;
            xr[idx] = f2b(w * b2f(xr[idx]));
            if (last) out_wlast[b * NFEAT + idx] = w;
        } else if (idx < 352) {
            xr[idx] = 0;   // kill emb residue: GEMM2 reads K=352
        }
    }
}

// ================= chunked parallel scan =================
__global__ __launch_bounds__(256) void seg_agg_k(const float* __restrict__ gates,
                                                 float* __restrict__ aggF,
                                                 float* __restrict__ aggL,
                                                 float* __restrict__ aggS) {
    int b = blockIdx.x >> 3;
    int cg = blockIdx.x & 7;
    int chunk = cg * 4 + (threadIdx.x >> 6);
    int e = threadIdx.x & 63;
    const float* gp = gates + ((size_t)b * SEQ + (size_t)chunk * CHUNK) * 256;
    float F = 0.f, L = -1e30f, s = 0.f;
#pragma unroll 4
    for (int t = 0; t < CHUNK; t++) {
        const float* q = gp + (size_t)t * 256;
        float li = q[e], lf = q[64 + e], z = q[128 + e];
        float Ln = fmaxf(L + lf, li);
        s = expf(L + lf - Ln) * s + expf(li - Ln) * z;
        L = Ln;
        F += lf;
    }
    int idx = (b * NCHUNK + chunk) * 64 + e;
    aggF[idx] = F; aggL[idx] = L; aggS[idx] = s;
}

// fully unrolled: all 96 loads issue up-front (one memory round-trip instead of 32 serial)
__global__ __launch_bounds__(64) void chunk_scan_k(const float* __restrict__ aggF,
                                                   const float* __restrict__ aggL,
                                                   const float* __restrict__ aggS,
                                                   float* __restrict__ stM,
                                                   float* __restrict__ stC) {
    int b = blockIdx.x;
    int e = threadIdx.x;
    float F[NCHUNK], L[NCHUNK], S[NCHUNK];
#pragma unroll
    for (int k = 0; k < NCHUNK; k++) {
        int idx = (b * NCHUNK + k) * 64 + e;
        F[k] = aggF[idx];
        L[k] = aggL[idx];
        S[k] = aggS[idx];
    }
    float m = 0.f, c = 0.f;
#pragma unroll
    for (int k = 0; k < NCHUNK; k++) {
        int idx = (b * NCHUNK + k) * 64 + e;
        stM[idx] = m; stC[idx] = c;
        float mn = fmaxf(m + F[k], L[k]);
        c = expf(m + F[k] - mn) * c + expf(L[k] - mn) * S[k];
        m = mn;
    }
}

__global__ __launch_bounds__(256) void replay_k(const float* __restrict__ gates,
                                                const float* __restrict__ stM,
                                                const float* __restrict__ stC,
                                                float* __restrict__ hs) {
    int b = blockIdx.x >> 3;
    int cg = blockIdx.x & 7;
    int chunk = cg * 4 + (threadIdx.x >> 6);
    int e = threadIdx.x & 63;
    int s0 = chunk * CHUNK;
    const float* gp = gates + ((size_t)b * SEQ + s0) * 256;
    float* hp = hs + ((size_t)b * SEQ + s0) * DSZ;
    int idx = (b * NCHUNK + chunk) * 64 + e;
    float m = stM[idx], c = stC[idx];
#pragma unroll 4
    for (int t = 0; t < CHUNK; t++) {
        const float* q = gp + (size_t)t * 256;
        float li = q[e], lf = q[64 + e], z = q[128 + e], o = q[192 + e];
        float mlf = m + lf;
        float mn = fmaxf(mlf, li);
        c = expf(mlf - mn) * c + expf(li - mn) * z;
        m = mn;
        hp[(size_t)t * DSZ + e] = o * tanhf(c);
    }
}

// ---------------- out-proj + residual + LN (h f32 in-place) + mu/rstd for next layer ----------------
// 32 tokens/block (8/wave), round-9 scalar layout (col = lane + 64*j: dense dword
// stores, 256B/instruction). ONLY change vs round 9: software-pipelined wp staging —
// next chunk prefetched into registers right after the barrier so the L2 round-trip
// hides under this chunk's ~2000-cycle compute phase.
__global__ __launch_bounds__(256) void outproj_k(const float* __restrict__ hs,
                                                 const float* __restrict__ wp,
                                                 const float* __restrict__ bp,
                                                 const float* __restrict__ nmg,
                                                 const float* __restrict__ nmb,
                                                 float* __restrict__ h,
                                                 float* __restrict__ mu,
                                                 float* __restrict__ rstd) {
    __shared__ float shs[32][DSZ];       // 8KB
    __shared__ float swp[16][DMODEL];    // 32KB
    int wv = threadIdx.x >> 6;
    int lane = threadIdx.x & 63;
    int tok0 = blockIdx.x * 32;

    // prologue: prefetch wp chunk 0 into regs + stage shs
    float4 pre[8];
    {
        const float4* srcw = (const float4*)wp;
#pragma unroll
        for (int i = 0; i < 8; i++) pre[i] = srcw[threadIdx.x + i * 256];
        const float4* src = (const float4*)(hs + (size_t)tok0 * DSZ);
        float4* dst = (float4*)&shs[0][0];
        dst[threadIdx.x] = src[threadIdx.x];
        dst[threadIdx.x + 256] = src[threadIdx.x + 256];
    }

    float acc[8][8] = {};
    for (int k0 = 0; k0 < DSZ; k0 += 16) {
        __syncthreads();   // prev chunk consumed (1st iter: orders shs stage too)
#pragma unroll
        for (int i = 0; i < 8; i++)
            ((float4*)&swp[0][0])[threadIdx.x + i * 256] = pre[i];
        __syncthreads();
        // issue next chunk's loads now — latency hides under this chunk's compute
        if (k0 + 16 < DSZ) {
            const float4* srcw = (const float4*)(wp + (size_t)(k0 + 16) * DMODEL);
#pragma unroll
            for (int i = 0; i < 8; i++) pre[i] = srcw[threadIdx.x + i * 256];
        }
#pragma unroll
        for (int k = 0; k < 16; k++) {
            float bv[8];
#pragma unroll
            for (int j = 0; j < 8; j++) bv[j] = swp[k][lane + 64 * j];
#pragma unroll
            for (int t = 0; t < 8; t++) {
                float av = shs[wv * 8 + t][k0 + k];
#pragma unroll
                for (int j = 0; j < 8; j++) acc[t][j] += av * bv[j];
            }
        }
    }

#pragma unroll
    for (int t = 0; t < 8; t++) {
        int tok = tok0 + wv * 8 + t;
        float u[8];
        float s = 0.f, sq = 0.f;
#pragma unroll
        for (int j = 0; j < 8; j++) {
            int col = lane + 64 * j;
            float v = h[(size_t)tok * DMODEL + col] + acc[t][j] + bp[col];
            u[j] = v;
            s += v; sq += v * v;
        }
#pragma unroll
        for (int o = 32; o > 0; o >>= 1) { s += __shfl_xor(s, o, 64); sq += __shfl_xor(sq, o, 64); }
        float mean = s * (1.f / DMODEL);
        float var = sq * (1.f / DMODEL) - mean * mean;
        float rs = rsqrtf(var + 1e-5f);
        float s2 = 0.f, sq2 = 0.f;
#pragma unroll
        for (int j = 0; j < 8; j++) {
            int col = lane + 64 * j;
            float v = (u[j] - mean) * rs * nmg[col] + nmb[col];
            h[(size_t)tok * DMODEL + col] = v;
            s2 += v; sq2 += v * v;
        }
#pragma unroll
        for (int o = 32; o > 0; o >>= 1) { s2 += __shfl_xor(s2, o, 64); sq2 += __shfl_xor(sq2, o, 64); }
        if (lane == 0) {
            float m2 = s2 * (1.f / DMODEL);
            float v2 = sq2 * (1.f / DMODEL) - m2 * m2;
            mu[tok] = m2;
            rstd[tok] = rsqrtf(v2 + 1e-5f);
        }
    }
}

// ---------------- heads on h[:, -1, :] (f32) ----------------
__global__ __launch_bounds__(64) void heads_k(const float* __restrict__ h,
                                              const float* hd15_w, const float* hd15_b,
                                              const float* hd30_w, const float* hd30_b,
                                              const float* hv_w, const float* hv_b,
                                              const float* hreg_w, const float* hreg_b,
                                              const float* hrng_w, const float* hrng_b,
                                              float* __restrict__ out) {
    int b = blockIdx.x;
    int lane = threadIdx.x;
    __shared__ float row[DMODEL];
    const float* hp = h + (size_t)(b * SEQ + SEQ - 1) * DMODEL;
#pragma unroll
    for (int i = 0; i < 8; i++) row[lane + 64 * i] = hp[lane + 64 * i];
    __syncthreads();
#pragma unroll
    for (int i = 0; i < 8; i++) out[448 + b * DMODEL + lane + 64 * i] = row[lane + 64 * i];
    if (lane < 14) {
        const float* w; const float* bb;
        int ncol, j, off;
        if (lane == 0)      { w = hd15_w; bb = hd15_b; ncol = 1; j = 0;         off = 0 + b; }
        else if (lane == 1) { w = hd30_w; bb = hd30_b; ncol = 1; j = 0;         off = 32 + b; }
        else if (lane < 5)  { j = lane - 2;  w = hv_w;   bb = hv_b;   ncol = 3; off = 64 + b * 3 + j; }
        else if (lane < 11) { j = lane - 5;  w = hreg_w; bb = hreg_b; ncol = 6; off = 160 + b * 6 + j; }
        else                { j = lane - 11; w = hrng_w; bb = hrng_b; ncol = 3; off = 352 + b * 3 + j; }
        float s = bb[j];
        for (int k = 0; k < DMODEL; k++) s += row[k] * w[k * ncol + j];
        out[off] = s;
    }
}

extern "C" void kernel_launch(void* const* d_in, const int* in_sizes, int n_in,
                              void* d_out, int out_size, void* d_ws, size_t ws_size,
                              hipStream_t stream) {
    (void)in_sizes; (void)n_in; (void)out_size; (void)ws_size;
    const float* x      = (const float*)d_in[0];
    const int*   rid    = (const int*)d_in[1];
    const float* emb    = (const float*)d_in[2];
    const float* grn_w1 = (const float*)d_in[3];
    const float* grn_b1 = (const float*)d_in[4];
    const float* grn_w2 = (const float*)d_in[5];
    const float* grn_b2 = (const float*)d_in[6];
    const float* in_w   = (const float*)d_in[7];
    const float* in_b   = (const float*)d_in[8];
    const float* ln_g   = (const float*)d_in[9];
    const float* ln_b   = (const float*)d_in[10];
    const float* wi     = (const float*)d_in[11];
    const float* bi     = (const float*)d_in[12];
    const float* wf     = (const float*)d_in[13];
    const float* bf_    = (const float*)d_in[14];
    const float* wz     = (const float*)d_in[15];
    const float* bz     = (const float*)d_in[16];
    const float* wo     = (const float*)d_in[17];
    const float* bo     = (const float*)d_in[18];
    const float* wp     = (const float*)d_in[19];
    const float* bp     = (const float*)d_in[20];
    const float* nm_g   = (const float*)d_in[21];
    const float* nm_b   = (const float*)d_in[22];

    float* out = (float*)d_out;
    char* W = (char*)d_ws;

    // ---- workspace layout (bytes), peak ~222.7 MB < 226,492,416 proven ----
    // [0, 134217728)    h f32 [MTOK][512]
    //   steps 2-3: hidden bf16 [MTOK][512] at +0 (dead before h written)
    //   steps 3-4: logits bf16 [MTOK][350] at +67108864 (dead before h written)
    // [134217728, 218103808)  region B:
    //   steps 1-5: xc bf16 [MTOK][384] (50.3 MB)
    //   loop:      gates f32 [MTOK][256] at +0, hsbuf f32 [MTOK][64] at +67108864
    // [218103808, ...)  misc: agg scratch, mu/rstd, converted weights, LN-stat accumulators
    float* h               = (float*)W;
    unsigned short* hidden = (unsigned short*)W;
    unsigned short* logits = (unsigned short*)(W + 67108864);
    char* RB = W + 134217728;
    unsigned short* xc = (unsigned short*)RB;
    float* gates  = (float*)RB;
    float* hsbuf  = (float*)(RB + 67108864);
    char* RM = W + 218103808;
    float* aggF  = (float*)(RM);
    float* aggL  = (float*)(RM + 262144);
    float* aggS  = (float*)(RM + 524288);
    float* stM   = (float*)(RM + 786432);
    float* stC   = (float*)(RM + 1048576);
    float* mu    = (float*)(RM + 1310720);
    float* rstd  = (float*)(RM + 1572864);
    unsigned short* w1t  = (unsigned short*)(RM + 1835008);  // [512][384]
    unsigned short* w2t  = (unsigned short*)(RM + 2228224);  // [384][512]
    unsigned short* inwt = (unsigned short*)(RM + 2621440);  // [512][352]
    unsigned short* gwt  = (unsigned short*)(RM + 2981888);  // [16][64][512]
    float* gbias         = (float*)(RM + 4030464);           // [4][256]
    float* statS         = (float*)(RM + 4034560);           // [MTOK] LN-stat Σv
    float* statQ         = (float*)(RM + 4296704);           // [MTOK] LN-stat Σv²

    // ---- preconvert (every call; graph-safe) ----
    build_xc_k<<<MTOK * 192 / 256, 256, 0, stream>>>(x, rid, emb, xc);
    tconv_k<<<dim3(2, 512), 256, 0, stream>>>(grn_w1, w1t, 382, 512, 384);
    tconv_k<<<dim3(2, 384), 256, 0, stream>>>(grn_w2, w2t, 512, 350, 512);
    tconv_k<<<dim3(2, 512), 256, 0, stream>>>(in_w, inwt, 350, 512, 352);
    tconv_g_k<<<dim3(2, 64, 16), 256, 0, stream>>>(wi, wf, wz, wo, gwt);
    gbias_k<<<1, 1024, 0, stream>>>(bi, bf_, bz, bo, gbias);
    hipMemsetAsync(statS, 0, 262144, stream);
    hipMemsetAsync(statQ, 0, 262144, stream);

    // GEMM0: hidden = elu(xc @ w1t^T + b1), bf16 out
    mgemm_k<0, 0><<<dim3(4, 512), 256, 0, stream>>>(xc, nullptr, w1t, grn_b1, nullptr, hidden,
                                                    nullptr, nullptr, nullptr, nullptr,
                                                    nullptr, nullptr,
                                                    384, 384, 384, 512, 512);
    // GEMM1: logits = hidden @ w2t^T + b2, bf16 out
    mgemm_k<0, 1><<<dim3(3, 512), 256, 0, stream>>>(hidden, nullptr, w2t, grn_b2, nullptr, logits,
                                                    nullptr, nullptr, nullptr, nullptr,
                                                    nullptr, nullptr,
                                                    512, 512, 512, 350, 350);
    // softmax + xw in-place into xc + weights last row
    softmax_xw_k<<<MTOK / 4, 256, 0, stream>>>(logits, xc, out + 16832);
    // GEMM2: h = xw @ inwt^T + in_b, f32 out; LN stats fused via atomics
    mgemm_k<0, 3><<<dim3(4, 512), 256, 0, stream>>>(xc, nullptr, inwt, in_b, h, nullptr,
                                                    nullptr, nullptr, nullptr, nullptr,
                                                    statS, statQ,
                                                    384, 352, 352, 512, 512);
    // finalize layer-0 LN stats (replaces ln_stats_k's 134MB h re-read)
    ln_fin_k<<<MTOK / 256, 256, 0, stream>>>(statS, statQ, mu, rstd);

    for (int l = 0; l < NLAYER; l++) {
        // gates = act(LN(h) @ gwt[l]^T + gbias[l]), f32 out; LN fused into A-staging
        mgemm_k<1, 2><<<dim3(2, 512), 256, 0, stream>>>(nullptr, h, gwt + (size_t)l * 131072,
                                                        gbias + l * 256, gates, nullptr,
                                                        mu, rstd,
                                                        ln_g + l * DMODEL, ln_b + l * DMODEL,
                                                        nullptr, nullptr,
                                                        512, 512, 512, 256, 256);
        seg_agg_k<<<BATCH * 8, 256, 0, stream>>>(gates, aggF, aggL, aggS);
        chunk_scan_k<<<BATCH, 64, 0, stream>>>(aggF, aggL, aggS, stM, stC);
        replay_k<<<BATCH * 8, 256, 0, stream>>>(gates, stM, stC, hsbuf);

        outproj_k<<<MTOK / 32, 256, 0, stream>>>(hsbuf,
                                                 wp + (size_t)l * DSZ * DMODEL,
                                                 bp + l * DMODEL,
                                                 nm_g + l * DMODEL,
                                                 nm_b + l * DMODEL,
                                                 h, mu, rstd);
    }

    heads_k<<<BATCH, 64, 0, stream>>>(h,
                                      (const float*)d_in[23], (const float*)d_in[24],
                                      (const float*)d_in[25], (const float*)d_in[26],
                                      (const float*)d_in[27], (const float*)d_in[28],
                                      (const float*)d_in[29], (const float*)d_in[30],
                                      (const float*)d_in[31], (const float*)d_in[32],
                                      out);
}

// Round 12
// 1289.750 us; speedup vs baseline: 1.1759x; 1.1759x over previous
//
#include <hip/hip_runtime.h>
#include <cmath>

#define NFEAT 350
#define DMODEL 512
#define NLAYER 4
#define DSZ 64
#define REG_E 32
#define BATCH 32
#define SEQ 2048
#define MTOK (BATCH * SEQ)      // 65536
#define CLAMP_V 20.0f

#define CHUNK 64
#define NCHUNK (SEQ / CHUNK)    // 32

typedef short bf16x8 __attribute__((ext_vector_type(8)));
typedef float f32x4 __attribute__((ext_vector_type(4)));

__device__ __forceinline__ unsigned short f2b(float v) {
    union { float f; unsigned int u; } x; x.f = v;
    unsigned int r = x.u + 0x7fffu + ((x.u >> 16) & 1u);
    return (unsigned short)(r >> 16);
}
__device__ __forceinline__ float b2f(unsigned short u) {
    union { unsigned int i; float f; } x; x.i = ((unsigned int)u) << 16;
    return x.f;
}
__device__ __forceinline__ unsigned int pack2(float a, float b) {
    return ((unsigned int)f2b(b) << 16) | f2b(a);
}

// ---------------- weight preconvert: dst[n][k] = bf16(src[k][n]), zero-padded ----------------
__global__ __launch_bounds__(256) void tconv_k(const float* __restrict__ src,
                                               unsigned short* __restrict__ dst,
                                               int K, int N, int Kpad) {
    int k = blockIdx.x * 256 + threadIdx.x;
    int n = blockIdx.y;
    if (k >= Kpad) return;
    float v = (k < K && n < N) ? src[(size_t)k * N + n] : 0.f;
    dst[(size_t)n * Kpad + k] = f2b(v);
}

// gates weights: z = l*4+g; src [512][64] -> dst[z][64 n][512 k]
__global__ __launch_bounds__(256) void tconv_g_k(const float* __restrict__ wi,
                                                 const float* __restrict__ wf,
                                                 const float* __restrict__ wz,
                                                 const float* __restrict__ wo,
                                                 unsigned short* __restrict__ dst) {
    int k = blockIdx.x * 256 + threadIdx.x;
    int n = blockIdx.y;
    int z = blockIdx.z;
    int l = z >> 2, g = z & 3;
    const float* src = (g == 0 ? wi : g == 1 ? wf : g == 2 ? wz : wo) + (size_t)l * DMODEL * DSZ;
    dst[(size_t)z * 32768 + (size_t)n * 512 + k] = f2b(src[(size_t)k * DSZ + n]);
}

__global__ __launch_bounds__(1024) void gbias_k(const float* bi, const float* bf_,
                                                const float* bz, const float* bo,
                                                float* __restrict__ gbias) {
    int t = threadIdx.x;                 // 1024 = L*256
    int l = t >> 8, r = t & 255, g = r >> 6, e = r & 63;
    const float* s = (g == 0 ? bi : g == 1 ? bf_ : g == 2 ? bz : bo);
    gbias[t] = s[l * 64 + e];
}

// ---------------- xc = bf16(concat(x, emb[rid], 0)) [MTOK][384] ----------------
__global__ __launch_bounds__(256) void build_xc_k(const float* __restrict__ x,
                                                  const int* __restrict__ rid,
                                                  const float* __restrict__ emb,
                                                  unsigned short* __restrict__ xc) {
    int i = blockIdx.x * 256 + threadIdx.x;      // MTOK*192
    int m = i / 192, p = i - m * 192;
    int k = p * 2;
    float a = 0.f, b = 0.f;
    if (k < 350) {
        const float2 v = *(const float2*)(x + (size_t)m * NFEAT + k);
        a = v.x; b = v.y;
    } else if (k < 382) {
        int r = rid[m];
        const float2 v = *(const float2*)(emb + r * REG_E + (k - 350));
        a = v.x; b = v.y;
    }
    ((unsigned int*)xc)[(size_t)m * 192 + p] = pack2(a, b);
}

// ---------------- MFMA GEMM: C = epi(A @ Bt^T' + bias) ----------------
// ALD 0: A bf16 [M][lda], direct 16B staging.
// ALD 1: A f32 [M][lda]; stage LN(A)= (a-mu[row])*rstd[row]*lng[k]+lnb[k] -> bf16.
// Bt [Npad][ldb] bf16 (row n = column n of B, k-contiguous).
// Tile 128x128x32, 256 threads = 4 waves (2x2 of 64x64).
// EPI 0: elu -> bf16 | 1: none -> bf16 | 2: gate act by n>>6 -> f32 | 3: none -> f32
//   EPI 3 extra: if statS != nullptr, accumulate per-token row sums S=Σv, Q=Σv² via
//   16-lane shfl reduce + atomicAdd (fuses ln_stats; finalized by ln_fin_k).
template <int ALD, int EPI>
__global__ __launch_bounds__(256) void mgemm_k(const unsigned short* __restrict__ Ab,
                                               const float* __restrict__ Af,
                                               const unsigned short* __restrict__ Bt,
                                               const float* __restrict__ bias,
                                               float* __restrict__ Cf,
                                               unsigned short* __restrict__ Cb,
                                               const float* __restrict__ muA,
                                               const float* __restrict__ rstdA,
                                               const float* __restrict__ lng,
                                               const float* __restrict__ lnb,
                                               float* __restrict__ statS,
                                               float* __restrict__ statQ,
                                               int lda, int ldb, int K, int N, int ldc) {
    __shared__ unsigned short As[128][40];   // 80B row stride: 16B-aligned, 2-way banks (free)
    __shared__ unsigned short Bs[128][40];
    const int tid = threadIdx.x;
    const int lane = tid & 63;
    const int wave = tid >> 6;
    const int l15 = lane & 15;
    const int quad = lane >> 4;
    const int wm = (wave >> 1) * 64;
    const int wn = (wave & 1) * 64;
    const size_t m0 = (size_t)blockIdx.y * 128;
    const int n0 = blockIdx.x * 128;

    const int sr = tid >> 2;                 // 0..63
    const int ku = tid & 3;                  // k-unit (8 elements)

    const unsigned short* Br0 = Bt + ((size_t)(n0 + sr)) * ldb + ku * 8;
    const unsigned short* Br1 = Br0 + (size_t)64 * ldb;

    const unsigned short* Ar0 = nullptr;
    const unsigned short* Ar1 = nullptr;
    const float* Fr0 = nullptr;
    const float* Fr1 = nullptr;
    float mu0 = 0.f, rs0 = 0.f, mu1 = 0.f, rs1 = 0.f;
    if (ALD == 0) {
        Ar0 = Ab + (m0 + sr) * (size_t)lda + ku * 8;
        Ar1 = Ar0 + (size_t)64 * lda;
    } else {
        Fr0 = Af + (m0 + sr) * (size_t)lda + ku * 8;
        Fr1 = Fr0 + (size_t)64 * lda;
        mu0 = muA[m0 + sr];   rs0 = rstdA[m0 + sr];
        mu1 = muA[m0 + sr + 64]; rs1 = rstdA[m0 + sr + 64];
    }

    f32x4 acc[4][4] = {};

    for (int k0 = 0; k0 < K; k0 += 32) {
        if (ALD == 0) {
            *(uint4*)&As[sr][ku * 8]      = *(const uint4*)(Ar0 + k0);
            *(uint4*)&As[sr + 64][ku * 8] = *(const uint4*)(Ar1 + k0);
        } else {
            float4 g0 = *(const float4*)(lng + k0 + ku * 8);
            float4 g1 = *(const float4*)(lng + k0 + ku * 8 + 4);
            float4 c0 = *(const float4*)(lnb + k0 + ku * 8);
            float4 c1 = *(const float4*)(lnb + k0 + ku * 8 + 4);
            {
                float4 v0 = *(const float4*)(Fr0 + k0);
                float4 v1 = *(const float4*)(Fr0 + k0 + 4);
                uint4 w;
                w.x = pack2((v0.x - mu0) * rs0 * g0.x + c0.x, (v0.y - mu0) * rs0 * g0.y + c0.y);
                w.y = pack2((v0.z - mu0) * rs0 * g0.z + c0.z, (v0.w - mu0) * rs0 * g0.w + c0.w);
                w.z = pack2((v1.x - mu0) * rs0 * g1.x + c1.x, (v1.y - mu0) * rs0 * g1.y + c1.y);
                w.w = pack2((v1.z - mu0) * rs0 * g1.z + c1.z, (v1.w - mu0) * rs0 * g1.w + c1.w);
                *(uint4*)&As[sr][ku * 8] = w;
            }
            {
                float4 v0 = *(const float4*)(Fr1 + k0);
                float4 v1 = *(const float4*)(Fr1 + k0 + 4);
                uint4 w;
                w.x = pack2((v0.x - mu1) * rs1 * g0.x + c0.x, (v0.y - mu1) * rs1 * g0.y + c0.y);
                w.y = pack2((v0.z - mu1) * rs1 * g0.z + c0.z, (v0.w - mu1) * rs1 * g0.w + c0.w);
                w.z = pack2((v1.x - mu1) * rs1 * g1.x + c1.x, (v1.y - mu1) * rs1 * g1.y + c1.y);
                w.w = pack2((v1.z - mu1) * rs1 * g1.z + c1.z, (v1.w - mu1) * rs1 * g1.w + c1.w);
                *(uint4*)&As[sr + 64][ku * 8] = w;
            }
        }
        *(uint4*)&Bs[sr][ku * 8]      = *(const uint4*)(Br0 + k0);
        *(uint4*)&Bs[sr + 64][ku * 8] = *(const uint4*)(Br1 + k0);
        __syncthreads();
        bf16x8 af[4], bf[4];
#pragma unroll
        for (int mt = 0; mt < 4; mt++)
            af[mt] = *(const bf16x8*)&As[wm + mt * 16 + l15][quad * 8];
#pragma unroll
        for (int nt = 0; nt < 4; nt++)
            bf[nt] = *(const bf16x8*)&Bs[wn + nt * 16 + l15][quad * 8];
#pragma unroll
        for (int mt = 0; mt < 4; mt++)
#pragma unroll
            for (int nt = 0; nt < 4; nt++)
                acc[mt][nt] = __builtin_amdgcn_mfma_f32_16x16x32_bf16(af[mt], bf[nt], acc[mt][nt], 0, 0, 0);
        __syncthreads();
    }

    float sA[4][4] = {}, qA[4][4] = {};

#pragma unroll
    for (int mt = 0; mt < 4; mt++) {
        int gmb = wm + mt * 16 + quad * 4;
#pragma unroll
        for (int nt = 0; nt < 4; nt++) {
            int gn = n0 + wn + nt * 16 + l15;
            if (gn < N) {
                float bv = bias[gn];
#pragma unroll
                for (int r = 0; r < 4; r++) {
                    size_t gm = m0 + gmb + r;
                    float v = acc[mt][nt][r] + bv;
                    if (EPI == 0) {
                        v = v > 0.f ? v : expm1f(v);
                        Cb[gm * (size_t)ldc + gn] = f2b(v);
                    } else if (EPI == 1) {
                        Cb[gm * (size_t)ldc + gn] = f2b(v);
                    } else if (EPI == 2) {
                        int g = gn >> 6;
                        if (g < 2) v = fminf(fmaxf(v, -CLAMP_V), CLAMP_V);
                        else if (g == 2) v = tanhf(v);
                        else v = 1.f / (1.f + expf(-v));
                        Cf[gm * (size_t)ldc + gn] = v;
                    } else {
                        Cf[gm * (size_t)ldc + gn] = v;
                        sA[mt][r] += v;
                        qA[mt][r] += v * v;
                    }
                }
            }
        }
    }

    if (EPI == 3 && statS != nullptr) {
#pragma unroll
        for (int mt = 0; mt < 4; mt++)
#pragma unroll
            for (int r = 0; r < 4; r++) {
                float s = sA[mt][r], q = qA[mt][r];
#pragma unroll
                for (int o = 1; o < 16; o <<= 1) {
                    s += __shfl_xor(s, o, 64);
                    q += __shfl_xor(q, o, 64);
                }
                if (l15 == 0) {
                    size_t gm = m0 + wm + mt * 16 + quad * 4 + r;
                    atomicAdd(&statS[gm], s);
                    atomicAdd(&statQ[gm], q);
                }
            }
    }
}

// finalize fused LN stats: (S, Q) -> (mu, rstd)
__global__ __launch_bounds__(256) void ln_fin_k(const float* __restrict__ statS,
                                                const float* __restrict__ statQ,
                                                float* __restrict__ mu,
                                                float* __restrict__ rstd) {
    int tok = blockIdx.x * 256 + threadIdx.x;
    float s = statS[tok], q = statQ[tok];
    float m = s * (1.f / DMODEL);
    float v = q * (1.f / DMODEL) - m * m;
    mu[tok] = m;
    rstd[tok] = rsqrtf(v + 1e-5f);
}

// ---------------- softmax over bf16 logits; writes xw=w*x in-place into xc; emits w last row ----------------
__global__ __launch_bounds__(256) void softmax_xw_k(const unsigned short* __restrict__ logits,
                                                    unsigned short* __restrict__ xc,
                                                    float* __restrict__ out_wlast) {
    int tok = blockIdx.x * 4 + (threadIdx.x >> 6);
    int lane = threadIdx.x & 63;
    const unsigned short* lr = logits + (size_t)tok * NFEAT;
    unsigned short* xr = xc + (size_t)tok * 384;
    float v[6];
    float mx = -1e30f;
#pragma unroll
    for (int i = 0; i < 6; i++) {
        int idx = lane + 64 * i;
        v[i] = (idx < NFEAT) ? b2f(lr[idx]) : -1e30f;
        mx = fmaxf(mx, v[i]);
    }
#pragma unroll
    for (int o = 32; o > 0; o >>= 1) mx = fmaxf(mx, __shfl_xor(mx, o, 64));
    float s = 0.f;
#pragma unroll
    for (int i = 0; i < 6; i++) { v[i] = expf(v[i] - mx); s += v[i]; }
#pragma unroll
    for (int o = 32; o > 0; o >>= 1) s += __shfl_xor(s, o, 64);
    float inv = 1.f / s;
    bool last = ((tok & (SEQ - 1)) == SEQ - 1);
    int b = tok >> 11;
#pragma unroll
    for (int i = 0; i < 6; i++) {
        int idx = lane + 64 * i;
        if (idx < NFEAT) {
            float w = v[i] * inv;
            xr[idx] = f2b(w * b2f(xr[idx]));
            if (last) out_wlast[b * NFEAT + idx] = w;
        } else if (idx < 352) {
            xr[idx] = 0;   // kill emb residue: GEMM2 reads K=352
        }
    }
}

// ================= chunked parallel scan =================
__global__ __launch_bounds__(256) void seg_agg_k(const float* __restrict__ gates,
                                                 float* __restrict__ aggF,
                                                 float* __restrict__ aggL,
                                                 float* __restrict__ aggS) {
    int b = blockIdx.x >> 3;
    int cg = blockIdx.x & 7;
    int chunk = cg * 4 + (threadIdx.x >> 6);
    int e = threadIdx.x & 63;
    const float* gp = gates + ((size_t)b * SEQ + (size_t)chunk * CHUNK) * 256;
    float F = 0.f, L = -1e30f, s = 0.f;
#pragma unroll 4
    for (int t = 0; t < CHUNK; t++) {
        const float* q = gp + (size_t)t * 256;
        float li = q[e], lf = q[64 + e], z = q[128 + e];
        float Ln = fmaxf(L + lf, li);
        s = expf(L + lf - Ln) * s + expf(li - Ln) * z;
        L = Ln;
        F += lf;
    }
    int idx = (b * NCHUNK + chunk) * 64 + e;
    aggF[idx] = F; aggL[idx] = L; aggS[idx] = s;
}

// fully unrolled: all 96 loads issue up-front (one memory round-trip instead of 32 serial)
__global__ __launch_bounds__(64) void chunk_scan_k(const float* __restrict__ aggF,
                                                   const float* __restrict__ aggL,
                                                   const float* __restrict__ aggS,
                                                   float* __restrict__ stM,
                                                   float* __restrict__ stC) {
    int b = blockIdx.x;
    int e = threadIdx.x;
    float F[NCHUNK], L[NCHUNK], S[NCHUNK];
#pragma unroll
    for (int k = 0; k < NCHUNK; k++) {
        int idx = (b * NCHUNK + k) * 64 + e;
        F[k] = aggF[idx];
        L[k] = aggL[idx];
        S[k] = aggS[idx];
    }
    float m = 0.f, c = 0.f;
#pragma unroll
    for (int k = 0; k < NCHUNK; k++) {
        int idx = (b * NCHUNK + k) * 64 + e;
        stM[idx] = m; stC[idx] = c;
        float mn = fmaxf(m + F[k], L[k]);
        c = expf(m + F[k] - mn) * c + expf(L[k] - mn) * S[k];
        m = mn;
    }
}

__global__ __launch_bounds__(256) void replay_k(const float* __restrict__ gates,
                                                const float* __restrict__ stM,
                                                const float* __restrict__ stC,
                                                float* __restrict__ hs) {
    int b = blockIdx.x >> 3;
    int cg = blockIdx.x & 7;
    int chunk = cg * 4 + (threadIdx.x >> 6);
    int e = threadIdx.x & 63;
    int s0 = chunk * CHUNK;
    const float* gp = gates + ((size_t)b * SEQ + s0) * 256;
    float* hp = hs + ((size_t)b * SEQ + s0) * DSZ;
    int idx = (b * NCHUNK + chunk) * 64 + e;
    float m = stM[idx], c = stC[idx];
#pragma unroll 4
    for (int t = 0; t < CHUNK; t++) {
        const float* q = gp + (size_t)t * 256;
        float li = q[e], lf = q[64 + e], z = q[128 + e], o = q[192 + e];
        float mlf = m + lf;
        float mn = fmaxf(mlf, li);
        c = expf(mlf - mn) * c + expf(li - mn) * z;
        m = mn;
        hp[(size_t)t * DSZ + e] = o * tanhf(c);
    }
}

// ---------------- out-proj + residual + LN (h f32 in-place) + mu/rstd for next layer ----------------
// Token-coarsened 2x: 32 tokens/block (8/wave). The 512 LDS bv-reads and the 128KB wp
// stage amortize over 2x tokens; wp L2 traffic and per-token barrier cost halve.
// NOTE: wp register-prefetch was tried twice (r10/r11) — the +32 VGPRs spill acc[8][8]
// to scratch (WRITE_SIZE 2x, 64KB/block = exactly acc). Keep the simple staging.
__global__ __launch_bounds__(256) void outproj_k(const float* __restrict__ hs,
                                                 const float* __restrict__ wp,
                                                 const float* __restrict__ bp,
                                                 const float* __restrict__ nmg,
                                                 const float* __restrict__ nmb,
                                                 float* __restrict__ h,
                                                 float* __restrict__ mu,
                                                 float* __restrict__ rstd) {
    __shared__ float shs[32][DSZ];       // 8KB
    __shared__ float swp[16][DMODEL];    // 32KB
    int wv = threadIdx.x >> 6;
    int lane = threadIdx.x & 63;
    int tok0 = blockIdx.x * 32;

    {
        const float4* src = (const float4*)(hs + (size_t)tok0 * DSZ);
        float4* dst = (float4*)&shs[0][0];
        dst[threadIdx.x] = src[threadIdx.x];
        dst[threadIdx.x + 256] = src[threadIdx.x + 256];
    }
    __syncthreads();

    float acc[8][8] = {};
    for (int k0 = 0; k0 < DSZ; k0 += 16) {
        const float4* src = (const float4*)(wp + (size_t)k0 * DMODEL);
#pragma unroll
        for (int i = 0; i < 8; i++)
            ((float4*)&swp[0][0])[threadIdx.x + i * 256] = src[threadIdx.x + i * 256];
        __syncthreads();
#pragma unroll
        for (int k = 0; k < 16; k++) {
            float bv[8];
#pragma unroll
            for (int j = 0; j < 8; j++) bv[j] = swp[k][lane + 64 * j];
#pragma unroll
            for (int t = 0; t < 8; t++) {
                float av = shs[wv * 8 + t][k0 + k];
#pragma unroll
                for (int j = 0; j < 8; j++) acc[t][j] += av * bv[j];
            }
        }
        __syncthreads();
    }

#pragma unroll
    for (int t = 0; t < 8; t++) {
        int tok = tok0 + wv * 8 + t;
        float u[8];
        float s = 0.f, sq = 0.f;
#pragma unroll
        for (int j = 0; j < 8; j++) {
            int col = lane + 64 * j;
            float v = h[(size_t)tok * DMODEL + col] + acc[t][j] + bp[col];
            u[j] = v;
            s += v; sq += v * v;
        }
#pragma unroll
        for (int o = 32; o > 0; o >>= 1) { s += __shfl_xor(s, o, 64); sq += __shfl_xor(sq, o, 64); }
        float mean = s * (1.f / DMODEL);
        float var = sq * (1.f / DMODEL) - mean * mean;
        float rs = rsqrtf(var + 1e-5f);
        float s2 = 0.f, sq2 = 0.f;
#pragma unroll
        for (int j = 0; j < 8; j++) {
            int col = lane + 64 * j;
            float v = (u[j] - mean) * rs * nmg[col] + nmb[col];
            h[(size_t)tok * DMODEL + col] = v;
            s2 += v; sq2 += v * v;
        }
#pragma unroll
        for (int o = 32; o > 0; o >>= 1) { s2 += __shfl_xor(s2, o, 64); sq2 += __shfl_xor(sq2, o, 64); }
        if (lane == 0) {
            float m2 = s2 * (1.f / DMODEL);
            float v2 = sq2 * (1.f / DMODEL) - m2 * m2;
            mu[tok] = m2;
            rstd[tok] = rsqrtf(v2 + 1e-5f);
        }
    }
}

// ---------------- heads on h[:, -1, :] (f32) ----------------
__global__ __launch_bounds__(64) void heads_k(const float* __restrict__ h,
                                              const float* hd15_w, const float* hd15_b,
                                              const float* hd30_w, const float* hd30_b,
                                              const float* hv_w, const float* hv_b,
                                              const float* hreg_w, const float* hreg_b,
                                              const float* hrng_w, const float* hrng_b,
                                              float* __restrict__ out) {
    int b = blockIdx.x;
    int lane = threadIdx.x;
    __shared__ float row[DMODEL];
    const float* hp = h + (size_t)(b * SEQ + SEQ - 1) * DMODEL;
#pragma unroll
    for (int i = 0; i < 8; i++) row[lane + 64 * i] = hp[lane + 64 * i];
    __syncthreads();
#pragma unroll
    for (int i = 0; i < 8; i++) out[448 + b * DMODEL + lane + 64 * i] = row[lane + 64 * i];
    if (lane < 14) {
        const float* w; const float* bb;
        int ncol, j, off;
        if (lane == 0)      { w = hd15_w; bb = hd15_b; ncol = 1; j = 0;         off = 0 + b; }
        else if (lane == 1) { w = hd30_w; bb = hd30_b; ncol = 1; j = 0;         off = 32 + b; }
        else if (lane < 5)  { j = lane - 2;  w = hv_w;   bb = hv_b;   ncol = 3; off = 64 + b * 3 + j; }
        else if (lane < 11) { j = lane - 5;  w = hreg_w; bb = hreg_b; ncol = 6; off = 160 + b * 6 + j; }
        else                { j = lane - 11; w = hrng_w; bb = hrng_b; ncol = 3; off = 352 + b * 3 + j; }
        float s = bb[j];
        for (int k = 0; k < DMODEL; k++) s += row[k] * w[k * ncol + j];
        out[off] = s;
    }
}

extern "C" void kernel_launch(void* const* d_in, const int* in_sizes, int n_in,
                              void* d_out, int out_size, void* d_ws, size_t ws_size,
                              hipStream_t stream) {
    (void)in_sizes; (void)n_in; (void)out_size; (void)ws_size;
    const float* x      = (const float*)d_in[0];
    const int*   rid    = (const int*)d_in[1];
    const float* emb    = (const float*)d_in[2];
    const float* grn_w1 = (const float*)d_in[3];
    const float* grn_b1 = (const float*)d_in[4];
    const float* grn_w2 = (const float*)d_in[5];
    const float* grn_b2 = (const float*)d_in[6];
    const float* in_w   = (const float*)d_in[7];
    const float* in_b   = (const float*)d_in[8];
    const float* ln_g   = (const float*)d_in[9];
    const float* ln_b   = (const float*)d_in[10];
    const float* wi     = (const float*)d_in[11];
    const float* bi     = (const float*)d_in[12];
    const float* wf     = (const float*)d_in[13];
    const float* bf_    = (const float*)d_in[14];
    const float* wz     = (const float*)d_in[15];
    const float* bz     = (const float*)d_in[16];
    const float* wo     = (const float*)d_in[17];
    const float* bo     = (const float*)d_in[18];
    const float* wp     = (const float*)d_in[19];
    const float* bp     = (const float*)d_in[20];
    const float* nm_g   = (const float*)d_in[21];
    const float* nm_b   = (const float*)d_in[22];

    float* out = (float*)d_out;
    char* W = (char*)d_ws;

    // ---- workspace layout (bytes), peak ~222.7 MB < 226,492,416 proven ----
    // [0, 134217728)    h f32 [MTOK][512]
    //   steps 2-3: hidden bf16 [MTOK][512] at +0 (dead before h written)
    //   steps 3-4: logits bf16 [MTOK][350] at +67108864 (dead before h written)
    // [134217728, 218103808)  region B:
    //   steps 1-5: xc bf16 [MTOK][384] (50.3 MB)
    //   loop:      gates f32 [MTOK][256] at +0, hsbuf f32 [MTOK][64] at +67108864
    // [218103808, ...)  misc: agg scratch, mu/rstd, converted weights, LN-stat accumulators
    float* h               = (float*)W;
    unsigned short* hidden = (unsigned short*)W;
    unsigned short* logits = (unsigned short*)(W + 67108864);
    char* RB = W + 134217728;
    unsigned short* xc = (unsigned short*)RB;
    float* gates  = (float*)RB;
    float* hsbuf  = (float*)(RB + 67108864);
    char* RM = W + 218103808;
    float* aggF  = (float*)(RM);
    float* aggL  = (float*)(RM + 262144);
    float* aggS  = (float*)(RM + 524288);
    float* stM   = (float*)(RM + 786432);
    float* stC   = (float*)(RM + 1048576);
    float* mu    = (float*)(RM + 1310720);
    float* rstd  = (float*)(RM + 1572864);
    unsigned short* w1t  = (unsigned short*)(RM + 1835008);  // [512][384]
    unsigned short* w2t  = (unsigned short*)(RM + 2228224);  // [384][512]
    unsigned short* inwt = (unsigned short*)(RM + 2621440);  // [512][352]
    unsigned short* gwt  = (unsigned short*)(RM + 2981888);  // [16][64][512]
    float* gbias         = (float*)(RM + 4030464);           // [4][256]
    float* statS         = (float*)(RM + 4034560);           // [MTOK] LN-stat Σv
    float* statQ         = (float*)(RM + 4296704);           // [MTOK] LN-stat Σv²

    // ---- preconvert (every call; graph-safe) ----
    build_xc_k<<<MTOK * 192 / 256, 256, 0, stream>>>(x, rid, emb, xc);
    tconv_k<<<dim3(2, 512), 256, 0, stream>>>(grn_w1, w1t, 382, 512, 384);
    tconv_k<<<dim3(2, 384), 256, 0, stream>>>(grn_w2, w2t, 512, 350, 512);
    tconv_k<<<dim3(2, 512), 256, 0, stream>>>(in_w, inwt, 350, 512, 352);
    tconv_g_k<<<dim3(2, 64, 16), 256, 0, stream>>>(wi, wf, wz, wo, gwt);
    gbias_k<<<1, 1024, 0, stream>>>(bi, bf_, bz, bo, gbias);
    hipMemsetAsync(statS, 0, 262144, stream);
    hipMemsetAsync(statQ, 0, 262144, stream);

    // GEMM0: hidden = elu(xc @ w1t^T + b1), bf16 out
    mgemm_k<0, 0><<<dim3(4, 512), 256, 0, stream>>>(xc, nullptr, w1t, grn_b1, nullptr, hidden,
                                                    nullptr, nullptr, nullptr, nullptr,
                                                    nullptr, nullptr,
                                                    384, 384, 384, 512, 512);
    // GEMM1: logits = hidden @ w2t^T + b2, bf16 out
    mgemm_k<0, 1><<<dim3(3, 512), 256, 0, stream>>>(hidden, nullptr, w2t, grn_b2, nullptr, logits,
                                                    nullptr, nullptr, nullptr, nullptr,
                                                    nullptr, nullptr,
                                                    512, 512, 512, 350, 350);
    // softmax + xw in-place into xc + weights last row
    softmax_xw_k<<<MTOK / 4, 256, 0, stream>>>(logits, xc, out + 16832);
    // GEMM2: h = xw @ inwt^T + in_b, f32 out; LN stats fused via atomics
    mgemm_k<0, 3><<<dim3(4, 512), 256, 0, stream>>>(xc, nullptr, inwt, in_b, h, nullptr,
                                                    nullptr, nullptr, nullptr, nullptr,
                                                    statS, statQ,
                                                    384, 352, 352, 512, 512);
    // finalize layer-0 LN stats (replaces ln_stats_k's 134MB h re-read)
    ln_fin_k<<<MTOK / 256, 256, 0, stream>>>(statS, statQ, mu, rstd);

    for (int l = 0; l < NLAYER; l++) {
        // gates = act(LN(h) @ gwt[l]^T + gbias[l]), f32 out; LN fused into A-staging
        mgemm_k<1, 2><<<dim3(2, 512), 256, 0, stream>>>(nullptr, h, gwt + (size_t)l * 131072,
                                                        gbias + l * 256, gates, nullptr,
                                                        mu, rstd,
                                                        ln_g + l * DMODEL, ln_b + l * DMODEL,
                                                        nullptr, nullptr,
                                                        512, 512, 512, 256, 256);
        seg_agg_k<<<BATCH * 8, 256, 0, stream>>>(gates, aggF, aggL, aggS);
        chunk_scan_k<<<BATCH, 64, 0, stream>>>(aggF, aggL, aggS, stM, stC);
        replay_k<<<BATCH * 8, 256, 0, stream>>>(gates, stM, stC, hsbuf);

        outproj_k<<<MTOK / 32, 256, 0, stream>>>(hsbuf,
                                                 wp + (size_t)l * DSZ * DMODEL,
                                                 bp + l * DMODEL,
                                                 nm_g + l * DMODEL,
                                                 nm_b + l * DMODEL,
                                                 h, mu, rstd);
    }

    heads_k<<<BATCH, 64, 0, stream>>>(h,
                                      (const float*)d_in[23], (const float*)d_in[24],
                                      (const float*)d_in[25], (const float*)d_in[26],
                                      (const float*)d_in[27], (const float*)d_in[28],
                                      (const float*)d_in[29], (const float*)d_in[30],
                                      (const float*)d_in[31], (const float*)d_in[32],
                                      out);
}